// Round 13
// baseline (2093.159 us; speedup 1.0000x reference)
//
#include <hip/hip_runtime.h>
#include <math.h>

#define NTOK 4096
#define HDIM 1024
#define NHEADS 16
#define HD 64
#define SEQ 2048
#define WSZ (HDIM*HDIM)
#define NM (NTOK*HDIM)
#define SQ7F 2.6457513110645906f   // float32(math.sqrt(7.0))
#define KC_BLK 384                 // OpenBLAS sgemm KC (k-panel) size

// Workspace (floats): wm4[0..3] | M (4*WSZ) | XD (NM, later ctx) | Q (NM, later cqm) | K | V
// M doubles as wmean stage-1 scratch (32768 floats) before k_wquant overwrites it.

// async global->LDS DMA, 16B per lane, zero VGPR cost (R9 lesson: register
// prefetch spills at this kernel's VGPR allocator ceiling).
__device__ __forceinline__ void gload_lds16(const float* g, float* l) {
  __builtin_amdgcn_global_load_lds(
      (const __attribute__((address_space(1))) void*)g,
      (__attribute__((address_space(3))) void*)l, 16, 0, 0);
}

// ---- wmean stage 1: one thread per 128-block, exact numpy base-case chains ----
__global__ __launch_bounds__(1024) void k_wmean_s1(const float* __restrict__ Wq,
                                                   const float* __restrict__ Wk,
                                                   const float* __restrict__ Wv,
                                                   const float* __restrict__ Wo,
                                                   float* __restrict__ bsG) {
  int w = blockIdx.y;
  const float* W = (w == 0) ? Wq : (w == 1) ? Wk : (w == 2) ? Wv : Wo;
  int idx = blockIdx.x * 1024 + threadIdx.x;   // 0..8191
  const float* a = W + (size_t)idx * 128;
  float4 f0 = *(const float4*)(a);
  float4 f1 = *(const float4*)(a + 4);
  float r0 = fabsf(f0.x), r1 = fabsf(f0.y), r2 = fabsf(f0.z), r3 = fabsf(f0.w);
  float r4 = fabsf(f1.x), r5 = fabsf(f1.y), r6 = fabsf(f1.z), r7 = fabsf(f1.w);
#pragma unroll
  for (int g = 1; g < 16; g++) {
    float4 g0 = *(const float4*)(a + g * 8);
    float4 g1 = *(const float4*)(a + g * 8 + 4);
    r0 = __fadd_rn(r0, fabsf(g0.x)); r1 = __fadd_rn(r1, fabsf(g0.y));
    r2 = __fadd_rn(r2, fabsf(g0.z)); r3 = __fadd_rn(r3, fabsf(g0.w));
    r4 = __fadd_rn(r4, fabsf(g1.x)); r5 = __fadd_rn(r5, fabsf(g1.y));
    r6 = __fadd_rn(r6, fabsf(g1.z)); r7 = __fadd_rn(r7, fabsf(g1.w));
  }
  bsG[w * 8192 + idx] = __fadd_rn(__fadd_rn(__fadd_rn(r0, r1), __fadd_rn(r2, r3)),
                                  __fadd_rn(__fadd_rn(r4, r5), __fadd_rn(r6, r7)));
}

// ---- wmean stage 2: exact numpy pairwise combine tree ----
__global__ __launch_bounds__(1024) void k_wmean_s2(const float* __restrict__ bsG,
                                                   float* __restrict__ wm4) {
  __shared__ float bsA[8192];
  __shared__ float bsB[4096];
  int w = blockIdx.x, t = threadIdx.x;
  for (int i = t; i < 8192; i += 1024) bsA[i] = bsG[w * 8192 + i];
  __syncthreads();
  float* cur = bsA;
  float* nxt = bsB;
  for (int len = 4096; len >= 1; len >>= 1) {
    for (int i = t; i < len; i += 1024)
      nxt[i] = __fadd_rn(cur[2 * i], cur[2 * i + 1]);
    __syncthreads();
    float* tmp = cur; cur = nxt; nxt = tmp;
  }
  if (t == 0) wm4[w] = cur[0] / 1048576.0f;   // exact /2^20
}

// ---- M = fl(fl(round-clip(W/(wm+1e-5)) * wm) * s) ----
__global__ void k_wquant_np(const float* __restrict__ Wq, const float* __restrict__ Wk,
                            const float* __restrict__ Wv, const float* __restrict__ Wo,
                            const float* __restrict__ wm4, float* __restrict__ M,
                            const float* __restrict__ sq, const float* __restrict__ sk,
                            const float* __restrict__ sv, const float* __restrict__ so) {
  int w = blockIdx.y;
  const float* W = (w == 0) ? Wq : (w == 1) ? Wk : (w == 2) ? Wv : Wo;
  float s = (w == 0) ? sq[0] : (w == 1) ? sk[0] : (w == 2) ? sv[0] : so[0];
  float wm = wm4[w];
  float wme = __fadd_rn(wm, 1e-5f);
  int i = blockIdx.x * 1024 + threadIdx.x * 4;
  float4 v = *(const float4*)(W + i);
  float4 o;
  o.x = __fmul_rn(__fmul_rn(fminf(fmaxf(rintf(__fdiv_rn(v.x, wme)), -1.f), 1.f), wm), s);
  o.y = __fmul_rn(__fmul_rn(fminf(fmaxf(rintf(__fdiv_rn(v.y, wme)), -1.f), 1.f), wm), s);
  o.z = __fmul_rn(__fmul_rn(fminf(fmaxf(rintf(__fdiv_rn(v.z, wme)), -1.f), 1.f), wm), s);
  o.w = __fmul_rn(__fmul_rn(fminf(fmaxf(rintf(__fdiv_rn(v.w, wme)), -1.f), 1.f), wm), s);
  *(float4*)(M + (size_t)w * WSZ + i) = o;
}

// ---- int4 quant: wave-parallel, exact numpy chains (unchanged, verified) ----
__global__ __launch_bounds__(256) void k_xquant_np(const float* __restrict__ x,
                                                   float* __restrict__ xd) {
  int t = threadIdx.x, wave = t >> 6, lane = t & 63;
  int n = blockIdx.x * 4 + wave;
  const float* row = x + (size_t)n * HDIM;
  int b = lane >> 3, j = lane & 7;
  const float* ch = row + b * 128 + j;
  float acc = fabsf(ch[0]);
#pragma unroll
  for (int i = 1; i < 16; i++) acc = __fadd_rn(acc, fabsf(ch[i * 8]));
  int gb = lane & ~7;
  float r0 = __shfl(acc, gb + 0), r1 = __shfl(acc, gb + 1),
        r2 = __shfl(acc, gb + 2), r3 = __shfl(acc, gb + 3),
        r4 = __shfl(acc, gb + 4), r5 = __shfl(acc, gb + 5),
        r6 = __shfl(acc, gb + 6), r7 = __shfl(acc, gb + 7);
  float bsum = __fadd_rn(__fadd_rn(__fadd_rn(r0, r1), __fadd_rn(r2, r3)),
                         __fadd_rn(__fadd_rn(r4, r5), __fadd_rn(r6, r7)));
  float b0 = __shfl(bsum, 0),  b1 = __shfl(bsum, 8),  b2 = __shfl(bsum, 16),
        b3 = __shfl(bsum, 24), b4 = __shfl(bsum, 32), b5 = __shfl(bsum, 40),
        b6 = __shfl(bsum, 48), b7 = __shfl(bsum, 56);
  float total = __fadd_rn(__fadd_rn(__fadd_rn(b0, b1), __fadd_rn(b2, b3)),
                          __fadd_rn(__fadd_rn(b4, b5), __fadd_rn(b6, b7)));
  float beta = total / 1024.0f;
  float bpe = __fadd_rn(beta, 1e-5f);
  float scale = __fmul_rn(beta, SQ7F);
  float* od = xd + (size_t)n * HDIM;
#pragma unroll
  for (int i = 0; i < 4; i++) {
    float4 v = *(const float4*)(row + i * 256 + lane * 4);
    float4 o;
    o.x = __fdiv_rn(__fmul_rn(fminf(fmaxf(rintf(__fdiv_rn(__fmul_rn(v.x, SQ7F), bpe)), -8.f), 7.f), scale), SQ7F);
    o.y = __fdiv_rn(__fmul_rn(fminf(fmaxf(rintf(__fdiv_rn(__fmul_rn(v.y, SQ7F), bpe)), -8.f), 7.f), scale), SQ7F);
    o.z = __fdiv_rn(__fmul_rn(fminf(fmaxf(rintf(__fdiv_rn(__fmul_rn(v.z, SQ7F), bpe)), -8.f), 7.f), scale), SQ7F);
    o.w = __fdiv_rn(__fmul_rn(fminf(fmaxf(rintf(__fdiv_rn(__fmul_rn(v.w, SQ7F), bpe)), -8.f), 7.f), scale), SQ7F);
    *(float4*)(od + i * 256 + lane * 4) = o;
  }
}

// ---- GEMM replicating BLAS sgemm accumulation (unchanged) ----
__global__ __launch_bounds__(256) void k_gemm_blas(const float* __restrict__ A,
                                                   const float* __restrict__ Bm,
                                                   float* __restrict__ C) {
  __shared__ __align__(16) float As[16 * 68];
  __shared__ __align__(16) float Bs[16 * 68];
  int t = threadIdx.x;
  int o0 = blockIdx.x * 64, n0 = blockIdx.y * 64;
  int lr = t >> 2, lc = (t & 3) * 4;
  const float* Ag = A + (size_t)(n0 + lr) * HDIM + lc;
  const float* Bg = Bm + (size_t)(o0 + lr) * HDIM + lc;
  int tn = (t & 15) * 4, to = (t >> 4) * 4;
  float acc[4][4] = {};
  float accP[4][4] = {};
  for (int kt = 0; kt < HDIM; kt += 16) {
    if (kt == KC_BLK || kt == 2 * KC_BLK) {
#pragma unroll
      for (int i = 0; i < 4; i++)
#pragma unroll
        for (int j = 0; j < 4; j++) {
          accP[i][j] = __fadd_rn(accP[i][j], acc[i][j]);
          acc[i][j] = 0.f;
        }
    }
    float4 a = *(const float4*)(Ag + kt);
    float4 b = *(const float4*)(Bg + kt);
    __syncthreads();
    float av[4] = {a.x, a.y, a.z, a.w};
    float bv[4] = {b.x, b.y, b.z, b.w};
#pragma unroll
    for (int u = 0; u < 4; u++) {
      As[(lc + u) * 68 + lr] = av[u];
      Bs[(lc + u) * 68 + lr] = bv[u];
    }
    __syncthreads();
#pragma unroll
    for (int kc = 0; kc < 16; kc++) {
      float4 a4 = *(const float4*)&As[kc * 68 + tn];
      float4 b4 = *(const float4*)&Bs[kc * 68 + to];
      float aa[4] = {a4.x, a4.y, a4.z, a4.w};
      float bb[4] = {b4.x, b4.y, b4.z, b4.w};
#pragma unroll
      for (int i = 0; i < 4; i++)
#pragma unroll
        for (int j = 0; j < 4; j++)
          acc[i][j] = __fmaf_rn(aa[i], bb[j], acc[i][j]);
    }
  }
#pragma unroll
  for (int i = 0; i < 4; i++) {
    float4 v;
    v.x = __fadd_rn(accP[i][0], acc[i][0]);
    v.y = __fadd_rn(accP[i][1], acc[i][1]);
    v.z = __fadd_rn(accP[i][2], acc[i][2]);
    v.w = __fadd_rn(accP[i][3], acc[i][3]);
    *(float4*)(C + (size_t)(n0 + tn + i) * HDIM + o0 + to) = v;
  }
}

// ---- attention: flash single-pass, 32-token tiles for 32KB LDS / 4 blk/CU ----
// R12 lesson: 48KB LDS did NOT raise occupancy (stuck 2 blk/CU, dur flat).
// This round: 32-token K/V tiles, BOTH double-buffered = exactly 32KB ->
// LDS allows 5 blk/CU, VGPR(116<=128) allows 4 -> expect 4 blk = 16 waves/CU.
// Per chunk (64 chunks): issue next tile DMA -> QK -> online softmax -> PV ->
// one barrier. Each lane owns ONE token (tk) at its d-half; dot products and
// swizzle identical to R10/R12 (0 conflicts); rescale cadence doubles
// (accepted reassociation class). Epilogue: R11-verified XOR stride-32
// scratch, bit-identical sum order, 4x2048 floats = exactly the 32KB arena.
__global__ __launch_bounds__(256, 2) void k_attn_np(const float* __restrict__ qb,
                                                    const float* __restrict__ kb,
                                                    const float* __restrict__ vb,
                                                    float* __restrict__ ctx) {
  __shared__ __align__(16) float Ks2[2][32 * 64];  // K tiles, swizzled rows
  __shared__ __align__(16) float Vs2[2][32 * 64];  // V tiles, swizzled rows
  int bh = blockIdx.y;
  int b = bh >> 4, h = bh & 15;
  int t = threadIdx.x, wave = t >> 6, lane = t & 63;
  int r0 = blockIdx.x * 8 + wave * 2;           // this wave's two q-rows
  size_t base = (size_t)b * SEQ * HDIM + h * HD;
  const float* qg0 = qb + base + (size_t)r0 * HDIM;
  const float* qg1 = qg0 + HDIM;

  // DMA staging map: wave w stages tile rows [8w, 8w+8), 2 calls x 1KB per
  // matrix. lane l writes granule (l&15) of row 8w + u*4 + (l>>4);
  // source granule g = (l&15) ^ (row&15).
  int lrow = lane >> 4, lgr = lane & 15;
  int rbase = wave << 3;

  int th = lane >> 5, tk = lane & 31;
  int th8 = th * 8;
  int sxA = tk & 15;
  int rA = tk * 64;

  float o0[32], o1[32];
#pragma unroll
  for (int j = 0; j < 32; j++) { o0[j] = 0.f; o1[j] = 0.f; }
  float m0 = -INFINITY, m1 = -INFINITY;
  float S0 = 0.f, S1 = 0.f;

  // prologue: DMA tile 0 into buffer 0
#pragma unroll
  for (int u = 0; u < 2; u++) {
    int row = rbase + u * 4 + lrow;
    int g = lgr ^ (row & 15);
    gload_lds16(kb + base + (size_t)row * HDIM + g * 4,
                &Ks2[0][(rbase + u * 4) * 64]);
    gload_lds16(vb + base + (size_t)row * HDIM + g * 4,
                &Vs2[0][(rbase + u * 4) * 64]);
  }
  __syncthreads();

  for (int c = 0; c < 64; c++) {
    int cur = c & 1;
    // issue next tile's DMA first (completes at this iteration's barrier)
    if (c < 63) {
      int nb = cur ^ 1;
      size_t goff = base + (size_t)(c + 1) * 32 * HDIM;
#pragma unroll
      for (int u = 0; u < 2; u++) {
        int row = rbase + u * 4 + lrow;
        int g = lgr ^ (row & 15);
        gload_lds16(kb + goff + (size_t)row * HDIM + g * 4,
                    &Ks2[nb][(rbase + u * 4) * 64]);
        gload_lds16(vb + goff + (size_t)row * HDIM + g * 4,
                    &Vs2[nb][(rbase + u * 4) * 64]);
      }
    }

    const float* Kb = &Ks2[cur][0];
    const float* Vb = &Vs2[cur][0];

    // === QK: lane computes d-half partial dot for its token tk ===
    float dA0 = 0.f, dA1 = 0.f;
#pragma unroll
    for (int i = 0; i < 8; i++) {
      int p4 = ((th8 + i) ^ sxA) * 4;
      float4 kA = *(const float4*)&Kb[rA + p4];
      float4 q0 = *(const float4*)(qg0 + th8 * 4 + i * 4);
      float4 q1 = *(const float4*)(qg1 + th8 * 4 + i * 4);
      dA0 = __fmaf_rn(q0.x, kA.x, dA0); dA0 = __fmaf_rn(q0.y, kA.y, dA0);
      dA0 = __fmaf_rn(q0.z, kA.z, dA0); dA0 = __fmaf_rn(q0.w, kA.w, dA0);
      dA1 = __fmaf_rn(q1.x, kA.x, dA1); dA1 = __fmaf_rn(q1.y, kA.y, dA1);
      dA1 = __fmaf_rn(q1.z, kA.z, dA1); dA1 = __fmaf_rn(q1.w, kA.w, dA1);
    }
    float sA0 = __fmul_rn(__fadd_rn(dA0, __shfl_xor(dA0, 32)), 0.125f);
    float sA1 = __fmul_rn(__fadd_rn(dA1, __shfl_xor(dA1, 32)), 0.125f);

    // online softmax, row 0 (halves duplicate; reduce over 32-lane half)
    float cm0 = sA0;
#pragma unroll
    for (int o = 16; o; o >>= 1) cm0 = fmaxf(cm0, __shfl_xor(cm0, o));
    if (cm0 > m0) {                              // wave-uniform
      float f = expf(m0 - cm0);                  // first chunk: expf(-inf)=0
      S0 = __fmul_rn(S0, f);
#pragma unroll
      for (int j = 0; j < 32; j++) o0[j] = __fmul_rn(o0[j], f);
      m0 = cm0;
    }
    float pA0 = expf(__fadd_rn(sA0, -m0));
    S0 = __fadd_rn(S0, pA0);

    // row 1
    float cm1 = sA1;
#pragma unroll
    for (int o = 16; o; o >>= 1) cm1 = fmaxf(cm1, __shfl_xor(cm1, o));
    if (cm1 > m1) {
      float f = expf(m1 - cm1);
      S1 = __fmul_rn(S1, f);
#pragma unroll
      for (int j = 0; j < 32; j++) o1[j] = __fmul_rn(o1[j], f);
      m1 = cm1;
    }
    float pA1 = expf(__fadd_rn(sA1, -m1));
    S1 = __fadd_rn(S1, pA1);

    // PV: lane's own token, p lane-local
#pragma unroll
    for (int i = 0; i < 8; i++) {
      int p4 = ((th8 + i) ^ sxA) * 4;
      float4 vA = *(const float4*)&Vb[rA + p4];
      o0[i * 4 + 0] = __fmaf_rn(pA0, vA.x, o0[i * 4 + 0]);
      o0[i * 4 + 1] = __fmaf_rn(pA0, vA.y, o0[i * 4 + 1]);
      o0[i * 4 + 2] = __fmaf_rn(pA0, vA.z, o0[i * 4 + 2]);
      o0[i * 4 + 3] = __fmaf_rn(pA0, vA.w, o0[i * 4 + 3]);
      o1[i * 4 + 0] = __fmaf_rn(pA1, vA.x, o1[i * 4 + 0]);
      o1[i * 4 + 1] = __fmaf_rn(pA1, vA.y, o1[i * 4 + 1]);
      o1[i * 4 + 2] = __fmaf_rn(pA1, vA.z, o1[i * 4 + 2]);
      o1[i * 4 + 3] = __fmaf_rn(pA1, vA.w, o1[i * 4 + 3]);
    }

    __syncthreads();   // waves done reading tile c; DMA for c+1 drained here
  }

  // denominators: reduce within 32-lane half (each token counted once)
#pragma unroll
  for (int o = 16; o; o >>= 1) S0 = __fadd_rn(S0, __shfl_xor(S0, o));
#pragma unroll
  for (int o = 16; o; o >>= 1) S1 = __fadd_rn(S1, __shfl_xor(S1, o));

  // epilogue: reduce o over the 32 token-lanes per d. Per-wave 2048-float
  // XOR-swizzled stride-32 region (R11-verified, bit-identical sum order);
  // 4 waves x 2048 floats exactly fill the 32KB tile arena.
  float* Osw = ((wave < 2) ? &Ks2[0][0] : &Vs2[0][0]) + (wave & 1) * 2048;
  int thd = lane >> 5, jd = lane & 31;
  size_t cb = base + (size_t)r0 * HDIM;
#pragma unroll
  for (int j = 0; j < 32; j++) Osw[lane * 32 + (j ^ (lane & 31))] = o0[j];
  float a0 = Osw[(thd * 32 + 0) * 32 + (jd ^ 0)];
#pragma unroll
  for (int s = 1; s < 32; s++)
    a0 = __fadd_rn(a0, Osw[(thd * 32 + s) * 32 + (jd ^ s)]);
  ctx[cb + lane] = __fdiv_rn(a0, S0);
#pragma unroll
  for (int j = 0; j < 32; j++) Osw[lane * 32 + (j ^ (lane & 31))] = o1[j];
  float a1 = Osw[(thd * 32 + 0) * 32 + (jd ^ 0)];
#pragma unroll
  for (int s = 1; s < 32; s++)
    a1 = __fadd_rn(a1, Osw[(thd * 32 + s) * 32 + (jd ^ s)]);
  ctx[cb + HDIM + lane] = __fdiv_rn(a1, S1);
}

// ---- int8 quant + topk (unchanged, verified) ----
__global__ __launch_bounds__(256) void k_ctxq_np(const float* __restrict__ ctx,
                                                 float* __restrict__ cqm) {
  int n = blockIdx.x, t = threadIdx.x;
  __shared__ float red[256];
  __shared__ int hist[129];
  __shared__ int tsh;
  float4 cv = *(const float4*)(ctx + (size_t)n * HDIM + t * 4);
  float mx = fmaxf(fmaxf(fabsf(cv.x), fabsf(cv.y)), fmaxf(fabsf(cv.z), fabsf(cv.w)));
  red[t] = mx; __syncthreads();
  for (int st = 128; st > 0; st >>= 1) {
    if (t < st) red[t] = fmaxf(red[t], red[t + st]);
    __syncthreads();
  }
  float gamma = red[0];
  if (t < 129) hist[t] = 0;
  __syncthreads();
  float gpe = __fadd_rn(gamma, 1e-5f);
  float q0 = fminf(fmaxf(rintf(__fdiv_rn(__fmul_rn(cv.x, 127.0f), gpe)), -128.f), 127.f);
  float q1 = fminf(fmaxf(rintf(__fdiv_rn(__fmul_rn(cv.y, 127.0f), gpe)), -128.f), 127.f);
  float q2 = fminf(fmaxf(rintf(__fdiv_rn(__fmul_rn(cv.z, 127.0f), gpe)), -128.f), 127.f);
  float q3 = fminf(fmaxf(rintf(__fdiv_rn(__fmul_rn(cv.w, 127.0f), gpe)), -128.f), 127.f);
  int a0 = (int)fabsf(q0), a1 = (int)fabsf(q1), a2 = (int)fabsf(q2), a3 = (int)fabsf(q3);
  atomicAdd(&hist[a0], 1); atomicAdd(&hist[a1], 1);
  atomicAdd(&hist[a2], 1); atomicAdd(&hist[a3], 1);
  __syncthreads();
  if (t < 129) {
    int cum = 0;
    for (int u = 0; u <= t; u++) cum += hist[u];
    if (cum >= 512 && cum - hist[t] < 512) tsh = t;
  }
  __syncthreads();
  int thr = tsh;
  float4 o;
  o.x = (a0 >= thr) ? __fdiv_rn(__fmul_rn(q0, gamma), 127.0f) : 0.f;
  o.y = (a1 >= thr) ? __fdiv_rn(__fmul_rn(q1, gamma), 127.0f) : 0.f;
  o.z = (a2 >= thr) ? __fdiv_rn(__fmul_rn(q2, gamma), 127.0f) : 0.f;
  o.w = (a3 >= thr) ? __fdiv_rn(__fmul_rn(q3, gamma), 127.0f) : 0.f;
  *(float4*)(cqm + (size_t)n * HDIM + t * 4) = o;
}

extern "C" void kernel_launch(void* const* d_in, const int* in_sizes, int n_in,
                              void* d_out, int out_size, void* d_ws, size_t ws_size,
                              hipStream_t stream) {
  const float* x  = (const float*)d_in[0];
  const float* Wq = (const float*)d_in[1];
  const float* Wk = (const float*)d_in[2];
  const float* Wv = (const float*)d_in[3];
  const float* Wo = (const float*)d_in[4];
  const float* sq = (const float*)d_in[5];
  const float* sk = (const float*)d_in[6];
  const float* sv = (const float*)d_in[7];
  const float* so = (const float*)d_in[8];
  float* out = (float*)d_out;

  float* F   = (float*)d_ws;
  float* wm4 = F;
  float* M   = F + 1024;
  float* XD  = M + (size_t)4 * WSZ;
  float* Q   = XD + (size_t)NM;
  float* K   = Q + (size_t)NM;
  float* V   = K + (size_t)NM;
  float* ctx = XD;
  float* cqm = Q;

  k_wmean_s1<<<dim3(8, 4), 1024, 0, stream>>>(Wq, Wk, Wv, Wo, M);  // M = scratch
  k_wmean_s2<<<4, 1024, 0, stream>>>(M, wm4);
  k_wquant_np<<<dim3(1024, 4), 256, 0, stream>>>(Wq, Wk, Wv, Wo, wm4, M, sq, sk, sv, so);
  k_xquant_np<<<1024, 256, 0, stream>>>(x, XD);

  k_gemm_blas<<<dim3(16, 64), 256, 0, stream>>>(XD, M + 0 * (size_t)WSZ, Q);
  k_gemm_blas<<<dim3(16, 64), 256, 0, stream>>>(XD, M + 1 * (size_t)WSZ, K);
  k_gemm_blas<<<dim3(16, 64), 256, 0, stream>>>(XD, M + 2 * (size_t)WSZ, V);

  k_attn_np<<<dim3(256, 32), 256, 0, stream>>>(Q, K, V, ctx);

  k_ctxq_np<<<4096, 256, 0, stream>>>(ctx, cqm);

  k_gemm_blas<<<dim3(16, 64), 256, 0, stream>>>(cqm, M + 3 * (size_t)WSZ, out);
}

// Round 14
// 1662.008 us; speedup vs baseline: 1.2594x; 1.2594x over previous
//
#include <hip/hip_runtime.h>
#include <math.h>

#define NTOK 4096
#define HDIM 1024
#define NHEADS 16
#define HD 64
#define SEQ 2048
#define WSZ (HDIM*HDIM)
#define NM (NTOK*HDIM)
#define SQ7F 2.6457513110645906f   // float32(math.sqrt(7.0))
#define KC_BLK 384                 // OpenBLAS sgemm KC (k-panel) size

// Workspace (floats): wm4[0..3] | M (4*WSZ) | XD (NM, later ctx) | Q (NM, later cqm) | K | V
// M doubles as wmean stage-1 scratch (32768 floats) before k_wquant overwrites it.

// async global->LDS DMA, 16B per lane, zero VGPR cost.
__device__ __forceinline__ void gload_lds16(const float* g, float* l) {
  __builtin_amdgcn_global_load_lds(
      (const __attribute__((address_space(1))) void*)g,
      (__attribute__((address_space(3))) void*)l, 16, 0, 0);
}

// ---- wmean stage 1: one thread per 128-block, exact numpy base-case chains ----
__global__ __launch_bounds__(1024) void k_wmean_s1(const float* __restrict__ Wq,
                                                   const float* __restrict__ Wk,
                                                   const float* __restrict__ Wv,
                                                   const float* __restrict__ Wo,
                                                   float* __restrict__ bsG) {
  int w = blockIdx.y;
  const float* W = (w == 0) ? Wq : (w == 1) ? Wk : (w == 2) ? Wv : Wo;
  int idx = blockIdx.x * 1024 + threadIdx.x;   // 0..8191
  const float* a = W + (size_t)idx * 128;
  float4 f0 = *(const float4*)(a);
  float4 f1 = *(const float4*)(a + 4);
  float r0 = fabsf(f0.x), r1 = fabsf(f0.y), r2 = fabsf(f0.z), r3 = fabsf(f0.w);
  float r4 = fabsf(f1.x), r5 = fabsf(f1.y), r6 = fabsf(f1.z), r7 = fabsf(f1.w);
#pragma unroll
  for (int g = 1; g < 16; g++) {
    float4 g0 = *(const float4*)(a + g * 8);
    float4 g1 = *(const float4*)(a + g * 8 + 4);
    r0 = __fadd_rn(r0, fabsf(g0.x)); r1 = __fadd_rn(r1, fabsf(g0.y));
    r2 = __fadd_rn(r2, fabsf(g0.z)); r3 = __fadd_rn(r3, fabsf(g0.w));
    r4 = __fadd_rn(r4, fabsf(g1.x)); r5 = __fadd_rn(r5, fabsf(g1.y));
    r6 = __fadd_rn(r6, fabsf(g1.z)); r7 = __fadd_rn(r7, fabsf(g1.w));
  }
  bsG[w * 8192 + idx] = __fadd_rn(__fadd_rn(__fadd_rn(r0, r1), __fadd_rn(r2, r3)),
                                  __fadd_rn(__fadd_rn(r4, r5), __fadd_rn(r6, r7)));
}

// ---- wmean stage 2: exact numpy pairwise combine tree ----
__global__ __launch_bounds__(1024) void k_wmean_s2(const float* __restrict__ bsG,
                                                   float* __restrict__ wm4) {
  __shared__ float bsA[8192];
  __shared__ float bsB[4096];
  int w = blockIdx.x, t = threadIdx.x;
  for (int i = t; i < 8192; i += 1024) bsA[i] = bsG[w * 8192 + i];
  __syncthreads();
  float* cur = bsA;
  float* nxt = bsB;
  for (int len = 4096; len >= 1; len >>= 1) {
    for (int i = t; i < len; i += 1024)
      nxt[i] = __fadd_rn(cur[2 * i], cur[2 * i + 1]);
    __syncthreads();
    float* tmp = cur; cur = nxt; nxt = tmp;
  }
  if (t == 0) wm4[w] = cur[0] / 1048576.0f;   // exact /2^20
}

// ---- M = fl(fl(round-clip(W/(wm+1e-5)) * wm) * s) ----
__global__ void k_wquant_np(const float* __restrict__ Wq, const float* __restrict__ Wk,
                            const float* __restrict__ Wv, const float* __restrict__ Wo,
                            const float* __restrict__ wm4, float* __restrict__ M,
                            const float* __restrict__ sq, const float* __restrict__ sk,
                            const float* __restrict__ sv, const float* __restrict__ so) {
  int w = blockIdx.y;
  const float* W = (w == 0) ? Wq : (w == 1) ? Wk : (w == 2) ? Wv : Wo;
  float s = (w == 0) ? sq[0] : (w == 1) ? sk[0] : (w == 2) ? sv[0] : so[0];
  float wm = wm4[w];
  float wme = __fadd_rn(wm, 1e-5f);
  int i = blockIdx.x * 1024 + threadIdx.x * 4;
  float4 v = *(const float4*)(W + i);
  float4 o;
  o.x = __fmul_rn(__fmul_rn(fminf(fmaxf(rintf(__fdiv_rn(v.x, wme)), -1.f), 1.f), wm), s);
  o.y = __fmul_rn(__fmul_rn(fminf(fmaxf(rintf(__fdiv_rn(v.y, wme)), -1.f), 1.f), wm), s);
  o.z = __fmul_rn(__fmul_rn(fminf(fmaxf(rintf(__fdiv_rn(v.z, wme)), -1.f), 1.f), wm), s);
  o.w = __fmul_rn(__fmul_rn(fminf(fmaxf(rintf(__fdiv_rn(v.w, wme)), -1.f), 1.f), wm), s);
  *(float4*)(M + (size_t)w * WSZ + i) = o;
}

// ---- int4 quant: wave-parallel, exact numpy chains (unchanged, verified) ----
__global__ __launch_bounds__(256) void k_xquant_np(const float* __restrict__ x,
                                                   float* __restrict__ xd) {
  int t = threadIdx.x, wave = t >> 6, lane = t & 63;
  int n = blockIdx.x * 4 + wave;
  const float* row = x + (size_t)n * HDIM;
  int b = lane >> 3, j = lane & 7;
  const float* ch = row + b * 128 + j;
  float acc = fabsf(ch[0]);
#pragma unroll
  for (int i = 1; i < 16; i++) acc = __fadd_rn(acc, fabsf(ch[i * 8]));
  int gb = lane & ~7;
  float r0 = __shfl(acc, gb + 0), r1 = __shfl(acc, gb + 1),
        r2 = __shfl(acc, gb + 2), r3 = __shfl(acc, gb + 3),
        r4 = __shfl(acc, gb + 4), r5 = __shfl(acc, gb + 5),
        r6 = __shfl(acc, gb + 6), r7 = __shfl(acc, gb + 7);
  float bsum = __fadd_rn(__fadd_rn(__fadd_rn(r0, r1), __fadd_rn(r2, r3)),
                         __fadd_rn(__fadd_rn(r4, r5), __fadd_rn(r6, r7)));
  float b0 = __shfl(bsum, 0),  b1 = __shfl(bsum, 8),  b2 = __shfl(bsum, 16),
        b3 = __shfl(bsum, 24), b4 = __shfl(bsum, 32), b5 = __shfl(bsum, 40),
        b6 = __shfl(bsum, 48), b7 = __shfl(bsum, 56);
  float total = __fadd_rn(__fadd_rn(__fadd_rn(b0, b1), __fadd_rn(b2, b3)),
                          __fadd_rn(__fadd_rn(b4, b5), __fadd_rn(b6, b7)));
  float beta = total / 1024.0f;
  float bpe = __fadd_rn(beta, 1e-5f);
  float scale = __fmul_rn(beta, SQ7F);
  float* od = xd + (size_t)n * HDIM;
#pragma unroll
  for (int i = 0; i < 4; i++) {
    float4 v = *(const float4*)(row + i * 256 + lane * 4);
    float4 o;
    o.x = __fdiv_rn(__fmul_rn(fminf(fmaxf(rintf(__fdiv_rn(__fmul_rn(v.x, SQ7F), bpe)), -8.f), 7.f), scale), SQ7F);
    o.y = __fdiv_rn(__fmul_rn(fminf(fmaxf(rintf(__fdiv_rn(__fmul_rn(v.y, SQ7F), bpe)), -8.f), 7.f), scale), SQ7F);
    o.z = __fdiv_rn(__fmul_rn(fminf(fmaxf(rintf(__fdiv_rn(__fmul_rn(v.z, SQ7F), bpe)), -8.f), 7.f), scale), SQ7F);
    o.w = __fdiv_rn(__fmul_rn(fminf(fmaxf(rintf(__fdiv_rn(__fmul_rn(v.w, SQ7F), bpe)), -8.f), 7.f), scale), SQ7F);
    *(float4*)(od + i * 256 + lane * 4) = o;
  }
}

// ---- GEMM replicating BLAS sgemm accumulation (unchanged) ----
__global__ __launch_bounds__(256) void k_gemm_blas(const float* __restrict__ A,
                                                   const float* __restrict__ Bm,
                                                   float* __restrict__ C) {
  __shared__ __align__(16) float As[16 * 68];
  __shared__ __align__(16) float Bs[16 * 68];
  int t = threadIdx.x;
  int o0 = blockIdx.x * 64, n0 = blockIdx.y * 64;
  int lr = t >> 2, lc = (t & 3) * 4;
  const float* Ag = A + (size_t)(n0 + lr) * HDIM + lc;
  const float* Bg = Bm + (size_t)(o0 + lr) * HDIM + lc;
  int tn = (t & 15) * 4, to = (t >> 4) * 4;
  float acc[4][4] = {};
  float accP[4][4] = {};
  for (int kt = 0; kt < HDIM; kt += 16) {
    if (kt == KC_BLK || kt == 2 * KC_BLK) {
#pragma unroll
      for (int i = 0; i < 4; i++)
#pragma unroll
        for (int j = 0; j < 4; j++) {
          accP[i][j] = __fadd_rn(accP[i][j], acc[i][j]);
          acc[i][j] = 0.f;
        }
    }
    float4 a = *(const float4*)(Ag + kt);
    float4 b = *(const float4*)(Bg + kt);
    __syncthreads();
    float av[4] = {a.x, a.y, a.z, a.w};
    float bv[4] = {b.x, b.y, b.z, b.w};
#pragma unroll
    for (int u = 0; u < 4; u++) {
      As[(lc + u) * 68 + lr] = av[u];
      Bs[(lc + u) * 68 + lr] = bv[u];
    }
    __syncthreads();
#pragma unroll
    for (int kc = 0; kc < 16; kc++) {
      float4 a4 = *(const float4*)&As[kc * 68 + tn];
      float4 b4 = *(const float4*)&Bs[kc * 68 + to];
      float aa[4] = {a4.x, a4.y, a4.z, a4.w};
      float bb[4] = {b4.x, b4.y, b4.z, b4.w};
#pragma unroll
      for (int i = 0; i < 4; i++)
#pragma unroll
        for (int j = 0; j < 4; j++)
          acc[i][j] = __fmaf_rn(aa[i], bb[j], acc[i][j]);
    }
  }
#pragma unroll
  for (int i = 0; i < 4; i++) {
    float4 v;
    v.x = __fadd_rn(accP[i][0], acc[i][0]);
    v.y = __fadd_rn(accP[i][1], acc[i][1]);
    v.z = __fadd_rn(accP[i][2], acc[i][2]);
    v.w = __fadd_rn(accP[i][3], acc[i][3]);
    *(float4*)(C + (size_t)(n0 + tn + i) * HDIM + o0 + to) = v;
  }
}

// ---- attention: R11 structure (512 thr, 8 waves, DMA dbuf) with (512,2) ----
// Occupancy model (R6..R13 data): DMA kernels cap at 2 blocks/CU regardless
// of LDS; 512-thr blocks -> 16 waves/CU (45% occ, R11-measured). R11 failed
// only because (512,4) capped VGPR at 64 (cap = 256/hint) -> spill. (512,2)
// -> cap 128 >= the ~104-116 needed -> no spill at 4 waves/SIMD.
// FP sequence bit-identical to R10/R11 (absmax 0.0078125).
__global__ __launch_bounds__(512, 2) void k_attn_np(const float* __restrict__ qb,
                                                    const float* __restrict__ kb,
                                                    const float* __restrict__ vb,
                                                    float* __restrict__ ctx) {
  __shared__ __align__(16) float Ks2[2][64 * 64];  // K tiles, swizzled rows
  __shared__ __align__(16) float Vs2[2][64 * 64];  // V tiles, swizzled rows
  int bh = blockIdx.y;
  int b = bh >> 4, h = bh & 15;
  int t = threadIdx.x, wave = t >> 6, lane = t & 63;
  int r0 = blockIdx.x * 16 + wave * 2;          // this wave's two q-rows
  size_t base = (size_t)b * SEQ * HDIM + h * HD;
  const float* qg0 = qb + base + (size_t)r0 * HDIM;
  const float* qg1 = qg0 + HDIM;

  // DMA staging map: wave w stages tile rows [8w, 8w+8), 2 calls x 1KB each
  // per matrix. lane l writes granule (l&15) of row 8w + u*4 + (l>>4);
  // source granule g = (l&15) ^ (row&15).
  int lrow = lane >> 4, lgr = lane & 15;
  int rbase = wave << 3;

  int th = lane >> 5, tk = lane & 31;
  int th8 = th * 8;
  int sxA = tk & 15;                            // == (tk+32)&15
  int rA = tk * 64, rB = (tk + 32) * 64;

  float o0[32], o1[32];
#pragma unroll
  for (int j = 0; j < 32; j++) { o0[j] = 0.f; o1[j] = 0.f; }
  float m0 = -INFINITY, m1 = -INFINITY;
  float S0 = 0.f, S1 = 0.f;

  // prologue: DMA tile 0 into buffer 0
#pragma unroll
  for (int u = 0; u < 2; u++) {
    int row = rbase + u * 4 + lrow;
    int g = lgr ^ (row & 15);
    const float* gk = kb + base + (size_t)row * HDIM + g * 4;
    const float* gv = vb + base + (size_t)row * HDIM + g * 4;
    gload_lds16(gk, &Ks2[0][(rbase + u * 4) * 64]);
    gload_lds16(gv, &Vs2[0][(rbase + u * 4) * 64]);
  }
  __syncthreads();

  for (int c = 0; c < 32; c++) {
    int cur = c & 1;
    // issue next tile's DMA first (completes at this iteration's barrier)
    if (c < 31) {
      int nb = cur ^ 1;
      size_t goff = base + (size_t)(c + 1) * 64 * HDIM;
#pragma unroll
      for (int u = 0; u < 2; u++) {
        int row = rbase + u * 4 + lrow;
        int g = lgr ^ (row & 15);
        const float* gk = kb + goff + (size_t)row * HDIM + g * 4;
        const float* gv = vb + goff + (size_t)row * HDIM + g * 4;
        gload_lds16(gk, &Ks2[nb][(rbase + u * 4) * 64]);
        gload_lds16(gv, &Vs2[nb][(rbase + u * 4) * 64]);
      }
    }

    const float* Kb = &Ks2[cur][0];
    const float* Vb = &Vs2[cur][0];

    // === QK (FP sequence identical to R10; swizzled addressing) ===
    float dA0 = 0.f, dB0 = 0.f, dA1 = 0.f, dB1 = 0.f;
#pragma unroll
    for (int i = 0; i < 8; i++) {
      int p4 = ((th8 + i) ^ sxA) * 4;
      float4 kA = *(const float4*)&Kb[rA + p4];
      float4 kB = *(const float4*)&Kb[rB + p4];
      float4 q0 = *(const float4*)(qg0 + th8 * 4 + i * 4);
      float4 q1 = *(const float4*)(qg1 + th8 * 4 + i * 4);
      dA0 = __fmaf_rn(q0.x, kA.x, dA0); dA0 = __fmaf_rn(q0.y, kA.y, dA0);
      dA0 = __fmaf_rn(q0.z, kA.z, dA0); dA0 = __fmaf_rn(q0.w, kA.w, dA0);
      dB0 = __fmaf_rn(q0.x, kB.x, dB0); dB0 = __fmaf_rn(q0.y, kB.y, dB0);
      dB0 = __fmaf_rn(q0.z, kB.z, dB0); dB0 = __fmaf_rn(q0.w, kB.w, dB0);
      dA1 = __fmaf_rn(q1.x, kA.x, dA1); dA1 = __fmaf_rn(q1.y, kA.y, dA1);
      dA1 = __fmaf_rn(q1.z, kA.z, dA1); dA1 = __fmaf_rn(q1.w, kA.w, dA1);
      dB1 = __fmaf_rn(q1.x, kB.x, dB1); dB1 = __fmaf_rn(q1.y, kB.y, dB1);
      dB1 = __fmaf_rn(q1.z, kB.z, dB1); dB1 = __fmaf_rn(q1.w, kB.w, dB1);
    }
    float sA0 = __fmul_rn(__fadd_rn(dA0, __shfl_xor(dA0, 32)), 0.125f);
    float sB0 = __fmul_rn(__fadd_rn(dB0, __shfl_xor(dB0, 32)), 0.125f);
    float sA1 = __fmul_rn(__fadd_rn(dA1, __shfl_xor(dA1, 32)), 0.125f);
    float sB1 = __fmul_rn(__fadd_rn(dB1, __shfl_xor(dB1, 32)), 0.125f);

    // online softmax, row 0
    float cm0 = fmaxf(sA0, sB0);
#pragma unroll
    for (int o = 16; o; o >>= 1) cm0 = fmaxf(cm0, __shfl_xor(cm0, o));
    if (cm0 > m0) {                              // wave-uniform
      float f = expf(m0 - cm0);                  // first chunk: expf(-inf)=0
      S0 = __fmul_rn(S0, f);
#pragma unroll
      for (int j = 0; j < 32; j++) o0[j] = __fmul_rn(o0[j], f);
      m0 = cm0;
    }
    float pA0 = expf(__fadd_rn(sA0, -m0));
    float pB0 = expf(__fadd_rn(sB0, -m0));
    S0 = __fadd_rn(S0, __fadd_rn(pA0, pB0));

    // row 1
    float cm1 = fmaxf(sA1, sB1);
#pragma unroll
    for (int o = 16; o; o >>= 1) cm1 = fmaxf(cm1, __shfl_xor(cm1, o));
    if (cm1 > m1) {
      float f = expf(m1 - cm1);
      S1 = __fmul_rn(S1, f);
#pragma unroll
      for (int j = 0; j < 32; j++) o1[j] = __fmul_rn(o1[j], f);
      m1 = cm1;
    }
    float pA1 = expf(__fadd_rn(sA1, -m1));
    float pB1 = expf(__fadd_rn(sB1, -m1));
    S1 = __fadd_rn(S1, __fadd_rn(pA1, pB1));

    // PV: each V read feeds both rows
#pragma unroll
    for (int i = 0; i < 8; i++) {
      int p4 = ((th8 + i) ^ sxA) * 4;
      float4 vA = *(const float4*)&Vb[rA + p4];
      float4 vB = *(const float4*)&Vb[rB + p4];
      o0[i * 4 + 0] = __fmaf_rn(pB0, vB.x, __fmaf_rn(pA0, vA.x, o0[i * 4 + 0]));
      o0[i * 4 + 1] = __fmaf_rn(pB0, vB.y, __fmaf_rn(pA0, vA.y, o0[i * 4 + 1]));
      o0[i * 4 + 2] = __fmaf_rn(pB0, vB.z, __fmaf_rn(pA0, vA.z, o0[i * 4 + 2]));
      o0[i * 4 + 3] = __fmaf_rn(pB0, vB.w, __fmaf_rn(pA0, vA.w, o0[i * 4 + 3]));
      o1[i * 4 + 0] = __fmaf_rn(pB1, vB.x, __fmaf_rn(pA1, vA.x, o1[i * 4 + 0]));
      o1[i * 4 + 1] = __fmaf_rn(pB1, vB.y, __fmaf_rn(pA1, vA.y, o1[i * 4 + 1]));
      o1[i * 4 + 2] = __fmaf_rn(pB1, vB.z, __fmaf_rn(pA1, vA.z, o1[i * 4 + 2]));
      o1[i * 4 + 3] = __fmaf_rn(pB1, vB.w, __fmaf_rn(pA1, vA.w, o1[i * 4 + 3]));
    }

    __syncthreads();   // waves done reading tile c; DMA for c+1 drained here
  }

  // denominators: reduce within 32-lane half (covers all tokens exactly once)
#pragma unroll
  for (int o = 16; o; o >>= 1) S0 = __fadd_rn(S0, __shfl_xor(S0, o));
#pragma unroll
  for (int o = 16; o; o >>= 1) S1 = __fadd_rn(S1, __shfl_xor(S1, o));

  // epilogue: reduce o over the 32 token-lanes per d. Per-wave 2048-float
  // region (8 waves exactly fill the 16K-float arena); stride-32 rows with
  // XOR(j^lane&31) swizzle (R11-verified). Sum order (s ascending) unchanged.
  float* Osw = ((wave < 4) ? &Ks2[0][0] : &Vs2[0][0]) + (wave & 3) * 2048;
  int thd = lane >> 5, jd = lane & 31;
  size_t cb = base + (size_t)r0 * HDIM;
#pragma unroll
  for (int j = 0; j < 32; j++) Osw[lane * 32 + (j ^ (lane & 31))] = o0[j];
  float a0 = Osw[(thd * 32 + 0) * 32 + (jd ^ 0)];
#pragma unroll
  for (int s = 1; s < 32; s++)
    a0 = __fadd_rn(a0, Osw[(thd * 32 + s) * 32 + (jd ^ s)]);
  ctx[cb + lane] = __fdiv_rn(a0, S0);
#pragma unroll
  for (int j = 0; j < 32; j++) Osw[lane * 32 + (j ^ (lane & 31))] = o1[j];
  float a1 = Osw[(thd * 32 + 0) * 32 + (jd ^ 0)];
#pragma unroll
  for (int s = 1; s < 32; s++)
    a1 = __fadd_rn(a1, Osw[(thd * 32 + s) * 32 + (jd ^ s)]);
  ctx[cb + HDIM + lane] = __fdiv_rn(a1, S1);
}

// ---- int8 quant + topk (unchanged, verified) ----
__global__ __launch_bounds__(256) void k_ctxq_np(const float* __restrict__ ctx,
                                                 float* __restrict__ cqm) {
  int n = blockIdx.x, t = threadIdx.x;
  __shared__ float red[256];
  __shared__ int hist[129];
  __shared__ int tsh;
  float4 cv = *(const float4*)(ctx + (size_t)n * HDIM + t * 4);
  float mx = fmaxf(fmaxf(fabsf(cv.x), fabsf(cv.y)), fmaxf(fabsf(cv.z), fabsf(cv.w)));
  red[t] = mx; __syncthreads();
  for (int st = 128; st > 0; st >>= 1) {
    if (t < st) red[t] = fmaxf(red[t], red[t + st]);
    __syncthreads();
  }
  float gamma = red[0];
  if (t < 129) hist[t] = 0;
  __syncthreads();
  float gpe = __fadd_rn(gamma, 1e-5f);
  float q0 = fminf(fmaxf(rintf(__fdiv_rn(__fmul_rn(cv.x, 127.0f), gpe)), -128.f), 127.f);
  float q1 = fminf(fmaxf(rintf(__fdiv_rn(__fmul_rn(cv.y, 127.0f), gpe)), -128.f), 127.f);
  float q2 = fminf(fmaxf(rintf(__fdiv_rn(__fmul_rn(cv.z, 127.0f), gpe)), -128.f), 127.f);
  float q3 = fminf(fmaxf(rintf(__fdiv_rn(__fmul_rn(cv.w, 127.0f), gpe)), -128.f), 127.f);
  int a0 = (int)fabsf(q0), a1 = (int)fabsf(q1), a2 = (int)fabsf(q2), a3 = (int)fabsf(q3);
  atomicAdd(&hist[a0], 1); atomicAdd(&hist[a1], 1);
  atomicAdd(&hist[a2], 1); atomicAdd(&hist[a3], 1);
  __syncthreads();
  if (t < 129) {
    int cum = 0;
    for (int u = 0; u <= t; u++) cum += hist[u];
    if (cum >= 512 && cum - hist[t] < 512) tsh = t;
  }
  __syncthreads();
  int thr = tsh;
  float4 o;
  o.x = (a0 >= thr) ? __fdiv_rn(__fmul_rn(q0, gamma), 127.0f) : 0.f;
  o.y = (a1 >= thr) ? __fdiv_rn(__fmul_rn(q1, gamma), 127.0f) : 0.f;
  o.z = (a2 >= thr) ? __fdiv_rn(__fmul_rn(q2, gamma), 127.0f) : 0.f;
  o.w = (a3 >= thr) ? __fdiv_rn(__fmul_rn(q3, gamma), 127.0f) : 0.f;
  *(float4*)(cqm + (size_t)n * HDIM + t * 4) = o;
}

extern "C" void kernel_launch(void* const* d_in, const int* in_sizes, int n_in,
                              void* d_out, int out_size, void* d_ws, size_t ws_size,
                              hipStream_t stream) {
  const float* x  = (const float*)d_in[0];
  const float* Wq = (const float*)d_in[1];
  const float* Wk = (const float*)d_in[2];
  const float* Wv = (const float*)d_in[3];
  const float* Wo = (const float*)d_in[4];
  const float* sq = (const float*)d_in[5];
  const float* sk = (const float*)d_in[6];
  const float* sv = (const float*)d_in[7];
  const float* so = (const float*)d_in[8];
  float* out = (float*)d_out;

  float* F   = (float*)d_ws;
  float* wm4 = F;
  float* M   = F + 1024;
  float* XD  = M + (size_t)4 * WSZ;
  float* Q   = XD + (size_t)NM;
  float* K   = Q + (size_t)NM;
  float* V   = K + (size_t)NM;
  float* ctx = XD;
  float* cqm = Q;

  k_wmean_s1<<<dim3(8, 4), 1024, 0, stream>>>(Wq, Wk, Wv, Wo, M);  // M = scratch
  k_wmean_s2<<<4, 1024, 0, stream>>>(M, wm4);
  k_wquant_np<<<dim3(1024, 4), 256, 0, stream>>>(Wq, Wk, Wv, Wo, wm4, M, sq, sk, sv, so);
  k_xquant_np<<<1024, 256, 0, stream>>>(x, XD);

  k_gemm_blas<<<dim3(16, 64), 256, 0, stream>>>(XD, M + 0 * (size_t)WSZ, Q);
  k_gemm_blas<<<dim3(16, 64), 256, 0, stream>>>(XD, M + 1 * (size_t)WSZ, K);
  k_gemm_blas<<<dim3(16, 64), 256, 0, stream>>>(XD, M + 2 * (size_t)WSZ, V);

  k_attn_np<<<dim3(128, 32), 512, 0, stream>>>(Q, K, V, ctx);

  k_ctxq_np<<<4096, 256, 0, stream>>>(ctx, cqm);

  k_gemm_blas<<<dim3(16, 64), 256, 0, stream>>>(cqm, M + 3 * (size_t)WSZ, out);
}

// Round 15
// 1500.811 us; speedup vs baseline: 1.3947x; 1.1074x over previous
//
#include <hip/hip_runtime.h>
#include <math.h>

#define NTOK 4096
#define HDIM 1024
#define NHEADS 16
#define HD 64
#define SEQ 2048
#define WSZ (HDIM*HDIM)
#define NM (NTOK*HDIM)
#define SQ7F 2.6457513110645906f   // float32(math.sqrt(7.0))
#define KC_BLK 384                 // OpenBLAS sgemm KC (k-panel) size

// Workspace (floats): wm4[0..3] | M (4*WSZ) | XD (NM, later ctx) | Q (NM, later cqm) | K | V
// M doubles as wmean stage-1 scratch (32768 floats) before k_wquant overwrites it.

// async global->LDS DMA, 16B per lane, zero VGPR cost.
__device__ __forceinline__ void gload_lds16(const float* g, float* l) {
  __builtin_amdgcn_global_load_lds(
      (const __attribute__((address_space(1))) void*)g,
      (__attribute__((address_space(3))) void*)l, 16, 0, 0);
}

// ---- wmean stage 1: one thread per 128-block, exact numpy base-case chains ----
__global__ __launch_bounds__(1024) void k_wmean_s1(const float* __restrict__ Wq,
                                                   const float* __restrict__ Wk,
                                                   const float* __restrict__ Wv,
                                                   const float* __restrict__ Wo,
                                                   float* __restrict__ bsG) {
  int w = blockIdx.y;
  const float* W = (w == 0) ? Wq : (w == 1) ? Wk : (w == 2) ? Wv : Wo;
  int idx = blockIdx.x * 1024 + threadIdx.x;   // 0..8191
  const float* a = W + (size_t)idx * 128;
  float4 f0 = *(const float4*)(a);
  float4 f1 = *(const float4*)(a + 4);
  float r0 = fabsf(f0.x), r1 = fabsf(f0.y), r2 = fabsf(f0.z), r3 = fabsf(f0.w);
  float r4 = fabsf(f1.x), r5 = fabsf(f1.y), r6 = fabsf(f1.z), r7 = fabsf(f1.w);
#pragma unroll
  for (int g = 1; g < 16; g++) {
    float4 g0 = *(const float4*)(a + g * 8);
    float4 g1 = *(const float4*)(a + g * 8 + 4);
    r0 = __fadd_rn(r0, fabsf(g0.x)); r1 = __fadd_rn(r1, fabsf(g0.y));
    r2 = __fadd_rn(r2, fabsf(g0.z)); r3 = __fadd_rn(r3, fabsf(g0.w));
    r4 = __fadd_rn(r4, fabsf(g1.x)); r5 = __fadd_rn(r5, fabsf(g1.y));
    r6 = __fadd_rn(r6, fabsf(g1.z)); r7 = __fadd_rn(r7, fabsf(g1.w));
  }
  bsG[w * 8192 + idx] = __fadd_rn(__fadd_rn(__fadd_rn(r0, r1), __fadd_rn(r2, r3)),
                                  __fadd_rn(__fadd_rn(r4, r5), __fadd_rn(r6, r7)));
}

// ---- wmean stage 2: exact numpy pairwise combine tree ----
__global__ __launch_bounds__(1024) void k_wmean_s2(const float* __restrict__ bsG,
                                                   float* __restrict__ wm4) {
  __shared__ float bsA[8192];
  __shared__ float bsB[4096];
  int w = blockIdx.x, t = threadIdx.x;
  for (int i = t; i < 8192; i += 1024) bsA[i] = bsG[w * 8192 + i];
  __syncthreads();
  float* cur = bsA;
  float* nxt = bsB;
  for (int len = 4096; len >= 1; len >>= 1) {
    for (int i = t; i < len; i += 1024)
      nxt[i] = __fadd_rn(cur[2 * i], cur[2 * i + 1]);
    __syncthreads();
    float* tmp = cur; cur = nxt; nxt = tmp;
  }
  if (t == 0) wm4[w] = cur[0] / 1048576.0f;   // exact /2^20
}

// ---- M = fl(fl(round-clip(W/(wm+1e-5)) * wm) * s) ----
__global__ void k_wquant_np(const float* __restrict__ Wq, const float* __restrict__ Wk,
                            const float* __restrict__ Wv, const float* __restrict__ Wo,
                            const float* __restrict__ wm4, float* __restrict__ M,
                            const float* __restrict__ sq, const float* __restrict__ sk,
                            const float* __restrict__ sv, const float* __restrict__ so) {
  int w = blockIdx.y;
  const float* W = (w == 0) ? Wq : (w == 1) ? Wk : (w == 2) ? Wv : Wo;
  float s = (w == 0) ? sq[0] : (w == 1) ? sk[0] : (w == 2) ? sv[0] : so[0];
  float wm = wm4[w];
  float wme = __fadd_rn(wm, 1e-5f);
  int i = blockIdx.x * 1024 + threadIdx.x * 4;
  float4 v = *(const float4*)(W + i);
  float4 o;
  o.x = __fmul_rn(__fmul_rn(fminf(fmaxf(rintf(__fdiv_rn(v.x, wme)), -1.f), 1.f), wm), s);
  o.y = __fmul_rn(__fmul_rn(fminf(fmaxf(rintf(__fdiv_rn(v.y, wme)), -1.f), 1.f), wm), s);
  o.z = __fmul_rn(__fmul_rn(fminf(fmaxf(rintf(__fdiv_rn(v.z, wme)), -1.f), 1.f), wm), s);
  o.w = __fmul_rn(__fmul_rn(fminf(fmaxf(rintf(__fdiv_rn(v.w, wme)), -1.f), 1.f), wm), s);
  *(float4*)(M + (size_t)w * WSZ + i) = o;
}

// ---- int4 quant: wave-parallel, exact numpy chains (unchanged, verified) ----
__global__ __launch_bounds__(256) void k_xquant_np(const float* __restrict__ x,
                                                   float* __restrict__ xd) {
  int t = threadIdx.x, wave = t >> 6, lane = t & 63;
  int n = blockIdx.x * 4 + wave;
  const float* row = x + (size_t)n * HDIM;
  int b = lane >> 3, j = lane & 7;
  const float* ch = row + b * 128 + j;
  float acc = fabsf(ch[0]);
#pragma unroll
  for (int i = 1; i < 16; i++) acc = __fadd_rn(acc, fabsf(ch[i * 8]));
  int gb = lane & ~7;
  float r0 = __shfl(acc, gb + 0), r1 = __shfl(acc, gb + 1),
        r2 = __shfl(acc, gb + 2), r3 = __shfl(acc, gb + 3),
        r4 = __shfl(acc, gb + 4), r5 = __shfl(acc, gb + 5),
        r6 = __shfl(acc, gb + 6), r7 = __shfl(acc, gb + 7);
  float bsum = __fadd_rn(__fadd_rn(__fadd_rn(r0, r1), __fadd_rn(r2, r3)),
                         __fadd_rn(__fadd_rn(r4, r5), __fadd_rn(r6, r7)));
  float b0 = __shfl(bsum, 0),  b1 = __shfl(bsum, 8),  b2 = __shfl(bsum, 16),
        b3 = __shfl(bsum, 24), b4 = __shfl(bsum, 32), b5 = __shfl(bsum, 40),
        b6 = __shfl(bsum, 48), b7 = __shfl(bsum, 56);
  float total = __fadd_rn(__fadd_rn(__fadd_rn(b0, b1), __fadd_rn(b2, b3)),
                          __fadd_rn(__fadd_rn(b4, b5), __fadd_rn(b6, b7)));
  float beta = total / 1024.0f;
  float bpe = __fadd_rn(beta, 1e-5f);
  float scale = __fmul_rn(beta, SQ7F);
  float* od = xd + (size_t)n * HDIM;
#pragma unroll
  for (int i = 0; i < 4; i++) {
    float4 v = *(const float4*)(row + i * 256 + lane * 4);
    float4 o;
    o.x = __fdiv_rn(__fmul_rn(fminf(fmaxf(rintf(__fdiv_rn(__fmul_rn(v.x, SQ7F), bpe)), -8.f), 7.f), scale), SQ7F);
    o.y = __fdiv_rn(__fmul_rn(fminf(fmaxf(rintf(__fdiv_rn(__fmul_rn(v.y, SQ7F), bpe)), -8.f), 7.f), scale), SQ7F);
    o.z = __fdiv_rn(__fmul_rn(fminf(fmaxf(rintf(__fdiv_rn(__fmul_rn(v.z, SQ7F), bpe)), -8.f), 7.f), scale), SQ7F);
    o.w = __fdiv_rn(__fmul_rn(fminf(fmaxf(rintf(__fdiv_rn(__fmul_rn(v.w, SQ7F), bpe)), -8.f), 7.f), scale), SQ7F);
    *(float4*)(od + i * 256 + lane * 4) = o;
  }
}

// ---- GEMM replicating BLAS sgemm accumulation (unchanged) ----
__global__ __launch_bounds__(256) void k_gemm_blas(const float* __restrict__ A,
                                                   const float* __restrict__ Bm,
                                                   float* __restrict__ C) {
  __shared__ __align__(16) float As[16 * 68];
  __shared__ __align__(16) float Bs[16 * 68];
  int t = threadIdx.x;
  int o0 = blockIdx.x * 64, n0 = blockIdx.y * 64;
  int lr = t >> 2, lc = (t & 3) * 4;
  const float* Ag = A + (size_t)(n0 + lr) * HDIM + lc;
  const float* Bg = Bm + (size_t)(o0 + lr) * HDIM + lc;
  int tn = (t & 15) * 4, to = (t >> 4) * 4;
  float acc[4][4] = {};
  float accP[4][4] = {};
  for (int kt = 0; kt < HDIM; kt += 16) {
    if (kt == KC_BLK || kt == 2 * KC_BLK) {
#pragma unroll
      for (int i = 0; i < 4; i++)
#pragma unroll
        for (int j = 0; j < 4; j++) {
          accP[i][j] = __fadd_rn(accP[i][j], acc[i][j]);
          acc[i][j] = 0.f;
        }
    }
    float4 a = *(const float4*)(Ag + kt);
    float4 b = *(const float4*)(Bg + kt);
    __syncthreads();
    float av[4] = {a.x, a.y, a.z, a.w};
    float bv[4] = {b.x, b.y, b.z, b.w};
#pragma unroll
    for (int u = 0; u < 4; u++) {
      As[(lc + u) * 68 + lr] = av[u];
      Bs[(lc + u) * 68 + lr] = bv[u];
    }
    __syncthreads();
#pragma unroll
    for (int kc = 0; kc < 16; kc++) {
      float4 a4 = *(const float4*)&As[kc * 68 + tn];
      float4 b4 = *(const float4*)&Bs[kc * 68 + to];
      float aa[4] = {a4.x, a4.y, a4.z, a4.w};
      float bb[4] = {b4.x, b4.y, b4.z, b4.w};
#pragma unroll
      for (int i = 0; i < 4; i++)
#pragma unroll
        for (int j = 0; j < 4; j++)
          acc[i][j] = __fmaf_rn(aa[i], bb[j], acc[i][j]);
    }
  }
#pragma unroll
  for (int i = 0; i < 4; i++) {
    float4 v;
    v.x = __fadd_rn(accP[i][0], acc[i][0]);
    v.y = __fadd_rn(accP[i][1], acc[i][1]);
    v.z = __fadd_rn(accP[i][2], acc[i][2]);
    v.w = __fadd_rn(accP[i][3], acc[i][3]);
    *(float4*)(C + (size_t)(n0 + tn + i) * HDIM + o0 + to) = v;
  }
}

// ---- attention: flash, 4 q-rows/wave, d-quarter lane split, DMA dbuf ----
// Occupancy is pinned at ~8 waves/CU for DMA kernels (R10/R12/R13/R14 all
// 23% regardless of LDS/block size) -> the remaining lever is per-pipe work.
// 4 rows/wave halves total LDS reads (dominant pipe, ~655us floor at R14):
// each staged K/V element now feeds 4 rows' FMAs. Lane = (dq = d-quarter,
// tk): owns tokens {tk,tk+16,tk+32,tk+48} over dims [dq*16,dq*16+16).
// o[4][16] = 64 regs; dots d[4][4] combine via xor16+xor32; softmax max/sum
// via xor1,2,4,8 within 16-lane groups (wave-uniform rescale preserved).
// Read granule (dq*4+j4)^tk covers 0..15 within each aligned 16-lane group
// -> same conflict-free class as R10 (measured 0). (256,2) -> 128 VGPR cap,
// est. peak ~120. WRITE_SIZE is the spill sentinel.
__global__ __launch_bounds__(256, 2) void k_attn_np(const float* __restrict__ qb,
                                                    const float* __restrict__ kb,
                                                    const float* __restrict__ vb,
                                                    float* __restrict__ ctx) {
  __shared__ __align__(16) float Ks2[2][64 * 64];  // K tiles, swizzled rows
  __shared__ __align__(16) float Vs2[2][64 * 64];  // V tiles, swizzled rows
  int bh = blockIdx.y;
  int b = bh >> 4, h = bh & 15;
  int t = threadIdx.x, wave = t >> 6, lane = t & 63;
  int r0 = blockIdx.x * 16 + wave * 4;          // this wave's four q-rows
  size_t base = (size_t)b * SEQ * HDIM + h * HD;
  const float* qg = qb + base + (size_t)r0 * HDIM;

  // DMA staging map (R10-identical): wave w stages tile rows [16w,16w+16),
  // 4 calls x 1KB per matrix. lane l writes granule (l&15) of row
  // 16w + u*4 + (l>>4); source granule g = (l&15) ^ (row&15).
  int lrow = lane >> 4, lgr = lane & 15;
  int rbase = wave << 4;

  int dq = lane >> 4, tk = lane & 15;
  int doff = dq * 16;
  int pbase = ((dq * 4) ^ tk) * 4;              // granule XOR tk, *4 floats
  // token j row base offsets in LDS floats: (tk + 16j)*64

  float o0[16], o1[16], o2[16], o3[16];
#pragma unroll
  for (int j = 0; j < 16; j++) { o0[j] = 0.f; o1[j] = 0.f; o2[j] = 0.f; o3[j] = 0.f; }
  float m0 = -INFINITY, m1 = -INFINITY, m2 = -INFINITY, m3 = -INFINITY;
  float S0 = 0.f, S1 = 0.f, S2 = 0.f, S3 = 0.f;

  // prologue: DMA tile 0 into buffer 0
#pragma unroll
  for (int u = 0; u < 4; u++) {
    int row = rbase + u * 4 + lrow;
    int g = lgr ^ (row & 15);
    gload_lds16(kb + base + (size_t)row * HDIM + g * 4,
                &Ks2[0][(rbase + u * 4) * 64]);
    gload_lds16(vb + base + (size_t)row * HDIM + g * 4,
                &Vs2[0][(rbase + u * 4) * 64]);
  }
  __syncthreads();

  for (int c = 0; c < 32; c++) {
    int cur = c & 1;
    if (c < 31) {
      int nb = cur ^ 1;
      size_t goff = base + (size_t)(c + 1) * 64 * HDIM;
#pragma unroll
      for (int u = 0; u < 4; u++) {
        int row = rbase + u * 4 + lrow;
        int g = lgr ^ (row & 15);
        gload_lds16(kb + goff + (size_t)row * HDIM + g * 4,
                    &Ks2[nb][(rbase + u * 4) * 64]);
        gload_lds16(vb + goff + (size_t)row * HDIM + g * 4,
                    &Vs2[nb][(rbase + u * 4) * 64]);
      }
    }

    const float* Kb = &Ks2[cur][0];
    const float* Vb = &Vs2[cur][0];

    // === QK: d[row][tokj] partial dots over this lane's d-quarter ===
    float d[4][4];
#pragma unroll
    for (int r = 0; r < 4; r++)
#pragma unroll
      for (int j = 0; j < 4; j++) d[r][j] = 0.f;
#pragma unroll
    for (int j4 = 0; j4 < 4; j4++) {
      int p4 = ((dq * 4 + j4) ^ tk) * 4;
      float4 k0 = *(const float4*)&Kb[(tk +  0) * 64 + p4];
      float4 k1 = *(const float4*)&Kb[(tk + 16) * 64 + p4];
      float4 k2 = *(const float4*)&Kb[(tk + 32) * 64 + p4];
      float4 k3 = *(const float4*)&Kb[(tk + 48) * 64 + p4];
#pragma unroll
      for (int r = 0; r < 4; r++) {
        float4 q = *(const float4*)(qg + (size_t)r * HDIM + doff + j4 * 4);
        d[r][0] = __fmaf_rn(q.x, k0.x, d[r][0]); d[r][0] = __fmaf_rn(q.y, k0.y, d[r][0]);
        d[r][0] = __fmaf_rn(q.z, k0.z, d[r][0]); d[r][0] = __fmaf_rn(q.w, k0.w, d[r][0]);
        d[r][1] = __fmaf_rn(q.x, k1.x, d[r][1]); d[r][1] = __fmaf_rn(q.y, k1.y, d[r][1]);
        d[r][1] = __fmaf_rn(q.z, k1.z, d[r][1]); d[r][1] = __fmaf_rn(q.w, k1.w, d[r][1]);
        d[r][2] = __fmaf_rn(q.x, k2.x, d[r][2]); d[r][2] = __fmaf_rn(q.y, k2.y, d[r][2]);
        d[r][2] = __fmaf_rn(q.z, k2.z, d[r][2]); d[r][2] = __fmaf_rn(q.w, k2.w, d[r][2]);
        d[r][3] = __fmaf_rn(q.x, k3.x, d[r][3]); d[r][3] = __fmaf_rn(q.y, k3.y, d[r][3]);
        d[r][3] = __fmaf_rn(q.z, k3.z, d[r][3]); d[r][3] = __fmaf_rn(q.w, k3.w, d[r][3]);
      }
    }
    // combine across the 4 dq groups; scale
    float p[4][4];
#pragma unroll
    for (int r = 0; r < 4; r++)
#pragma unroll
      for (int j = 0; j < 4; j++) {
        float v = d[r][j];
        v = __fadd_rn(v, __shfl_xor(v, 16));
        v = __fadd_rn(v, __shfl_xor(v, 32));
        p[r][j] = __fmul_rn(v, 0.125f);
      }

    // === online softmax per row (rows unrolled; branch wave-uniform) ===
#define SOFTMAX_ROW(R, MR, SR, OR)                                            \
    {                                                                         \
      float cm = fmaxf(fmaxf(p[R][0], p[R][1]), fmaxf(p[R][2], p[R][3]));     \
      cm = fmaxf(cm, __shfl_xor(cm, 1));                                      \
      cm = fmaxf(cm, __shfl_xor(cm, 2));                                      \
      cm = fmaxf(cm, __shfl_xor(cm, 4));                                      \
      cm = fmaxf(cm, __shfl_xor(cm, 8));                                      \
      if (cm > MR) {                                                          \
        float f = expf(MR - cm);                                              \
        SR = __fmul_rn(SR, f);                                                \
        _Pragma("unroll")                                                     \
        for (int j = 0; j < 16; j++) OR[j] = __fmul_rn(OR[j], f);             \
        MR = cm;                                                              \
      }                                                                       \
      p[R][0] = expf(__fadd_rn(p[R][0], -MR));                                \
      p[R][1] = expf(__fadd_rn(p[R][1], -MR));                                \
      p[R][2] = expf(__fadd_rn(p[R][2], -MR));                                \
      p[R][3] = expf(__fadd_rn(p[R][3], -MR));                                \
      SR = __fadd_rn(SR, p[R][0]); SR = __fadd_rn(SR, p[R][1]);               \
      SR = __fadd_rn(SR, p[R][2]); SR = __fadd_rn(SR, p[R][3]);               \
    }
    SOFTMAX_ROW(0, m0, S0, o0)
    SOFTMAX_ROW(1, m1, S1, o1)
    SOFTMAX_ROW(2, m2, S2, o2)
    SOFTMAX_ROW(3, m3, S3, o3)
#undef SOFTMAX_ROW

    // === PV: each V read feeds 4 rows ===
#pragma unroll
    for (int j4 = 0; j4 < 4; j4++) {
      int p4 = ((dq * 4 + j4) ^ tk) * 4;
      float4 v0 = *(const float4*)&Vb[(tk +  0) * 64 + p4];
      float4 v1 = *(const float4*)&Vb[(tk + 16) * 64 + p4];
      float4 v2 = *(const float4*)&Vb[(tk + 32) * 64 + p4];
      float4 v3 = *(const float4*)&Vb[(tk + 48) * 64 + p4];
      int jb = j4 * 4;
#define PV_ROW(R, OR)                                                          \
      OR[jb+0] = __fmaf_rn(p[R][3], v3.x, __fmaf_rn(p[R][2], v2.x,             \
                 __fmaf_rn(p[R][1], v1.x, __fmaf_rn(p[R][0], v0.x, OR[jb+0])))); \
      OR[jb+1] = __fmaf_rn(p[R][3], v3.y, __fmaf_rn(p[R][2], v2.y,             \
                 __fmaf_rn(p[R][1], v1.y, __fmaf_rn(p[R][0], v0.y, OR[jb+1])))); \
      OR[jb+2] = __fmaf_rn(p[R][3], v3.z, __fmaf_rn(p[R][2], v2.z,             \
                 __fmaf_rn(p[R][1], v1.z, __fmaf_rn(p[R][0], v0.z, OR[jb+2])))); \
      OR[jb+3] = __fmaf_rn(p[R][3], v3.w, __fmaf_rn(p[R][2], v2.w,             \
                 __fmaf_rn(p[R][1], v1.w, __fmaf_rn(p[R][0], v0.w, OR[jb+3]))));
      PV_ROW(0, o0)
      PV_ROW(1, o1)
      PV_ROW(2, o2)
      PV_ROW(3, o3)
#undef PV_ROW
    }

    __syncthreads();   // waves done reading tile c; DMA for c+1 drained here
  }

  // denominators: sum over the 16 tk lanes (dq copies identical)
#pragma unroll
  for (int o = 8; o; o >>= 1) {
    S0 = __fadd_rn(S0, __shfl_xor(S0, o));
    S1 = __fadd_rn(S1, __shfl_xor(S1, o));
    S2 = __fadd_rn(S2, __shfl_xor(S2, o));
    S3 = __fadd_rn(S3, __shfl_xor(S3, o));
  }

  // epilogue: sum o over the 16 tk lanes per dim. Per-wave LDS scratch
  // (tiles dead): lane writes its 16 values at [lane*17+j]; reader for
  // dim lane ( = dq_out*16 + j_out) sums rows dq_out*16+s, s ascending.
  float* Osw = &Ks2[0][0] + wave * 1100;
  int dqo = lane >> 4, jo = lane & 15;
  size_t cb = base + (size_t)r0 * HDIM;
#define EPI_ROW(R, OR, SR)                                                    \
  {                                                                           \
    _Pragma("unroll")                                                         \
    for (int j = 0; j < 16; j++) Osw[lane * 17 + j] = OR[j];                  \
    float a = Osw[(dqo * 16 + 0) * 17 + jo];                                  \
    _Pragma("unroll")                                                         \
    for (int s = 1; s < 16; s++)                                              \
      a = __fadd_rn(a, Osw[(dqo * 16 + s) * 17 + jo]);                        \
    ctx[cb + (size_t)R * HDIM + lane] = __fdiv_rn(a, SR);                     \
  }
  EPI_ROW(0, o0, S0)
  EPI_ROW(1, o1, S1)
  EPI_ROW(2, o2, S2)
  EPI_ROW(3, o3, S3)
#undef EPI_ROW
}

// ---- int8 quant + topk (unchanged, verified) ----
__global__ __launch_bounds__(256) void k_ctxq_np(const float* __restrict__ ctx,
                                                 float* __restrict__ cqm) {
  int n = blockIdx.x, t = threadIdx.x;
  __shared__ float red[256];
  __shared__ int hist[129];
  __shared__ int tsh;
  float4 cv = *(const float4*)(ctx + (size_t)n * HDIM + t * 4);
  float mx = fmaxf(fmaxf(fabsf(cv.x), fabsf(cv.y)), fmaxf(fabsf(cv.z), fabsf(cv.w)));
  red[t] = mx; __syncthreads();
  for (int st = 128; st > 0; st >>= 1) {
    if (t < st) red[t] = fmaxf(red[t], red[t + st]);
    __syncthreads();
  }
  float gamma = red[0];
  if (t < 129) hist[t] = 0;
  __syncthreads();
  float gpe = __fadd_rn(gamma, 1e-5f);
  float q0 = fminf(fmaxf(rintf(__fdiv_rn(__fmul_rn(cv.x, 127.0f), gpe)), -128.f), 127.f);
  float q1 = fminf(fmaxf(rintf(__fdiv_rn(__fmul_rn(cv.y, 127.0f), gpe)), -128.f), 127.f);
  float q2 = fminf(fmaxf(rintf(__fdiv_rn(__fmul_rn(cv.z, 127.0f), gpe)), -128.f), 127.f);
  float q3 = fminf(fmaxf(rintf(__fdiv_rn(__fmul_rn(cv.w, 127.0f), gpe)), -128.f), 127.f);
  int a0 = (int)fabsf(q0), a1 = (int)fabsf(q1), a2 = (int)fabsf(q2), a3 = (int)fabsf(q3);
  atomicAdd(&hist[a0], 1); atomicAdd(&hist[a1], 1);
  atomicAdd(&hist[a2], 1); atomicAdd(&hist[a3], 1);
  __syncthreads();
  if (t < 129) {
    int cum = 0;
    for (int u = 0; u <= t; u++) cum += hist[u];
    if (cum >= 512 && cum - hist[t] < 512) tsh = t;
  }
  __syncthreads();
  int thr = tsh;
  float4 o;
  o.x = (a0 >= thr) ? __fdiv_rn(__fmul_rn(q0, gamma), 127.0f) : 0.f;
  o.y = (a1 >= thr) ? __fdiv_rn(__fmul_rn(q1, gamma), 127.0f) : 0.f;
  o.z = (a2 >= thr) ? __fdiv_rn(__fmul_rn(q2, gamma), 127.0f) : 0.f;
  o.w = (a3 >= thr) ? __fdiv_rn(__fmul_rn(q3, gamma), 127.0f) : 0.f;
  *(float4*)(cqm + (size_t)n * HDIM + t * 4) = o;
}

extern "C" void kernel_launch(void* const* d_in, const int* in_sizes, int n_in,
                              void* d_out, int out_size, void* d_ws, size_t ws_size,
                              hipStream_t stream) {
  const float* x  = (const float*)d_in[0];
  const float* Wq = (const float*)d_in[1];
  const float* Wk = (const float*)d_in[2];
  const float* Wv = (const float*)d_in[3];
  const float* Wo = (const float*)d_in[4];
  const float* sq = (const float*)d_in[5];
  const float* sk = (const float*)d_in[6];
  const float* sv = (const float*)d_in[7];
  const float* so = (const float*)d_in[8];
  float* out = (float*)d_out;

  float* F   = (float*)d_ws;
  float* wm4 = F;
  float* M   = F + 1024;
  float* XD  = M + (size_t)4 * WSZ;
  float* Q   = XD + (size_t)NM;
  float* K   = Q + (size_t)NM;
  float* V   = K + (size_t)NM;
  float* ctx = XD;
  float* cqm = Q;

  k_wmean_s1<<<dim3(8, 4), 1024, 0, stream>>>(Wq, Wk, Wv, Wo, M);  // M = scratch
  k_wmean_s2<<<4, 1024, 0, stream>>>(M, wm4);
  k_wquant_np<<<dim3(1024, 4), 256, 0, stream>>>(Wq, Wk, Wv, Wo, wm4, M, sq, sk, sv, so);
  k_xquant_np<<<1024, 256, 0, stream>>>(x, XD);

  k_gemm_blas<<<dim3(16, 64), 256, 0, stream>>>(XD, M + 0 * (size_t)WSZ, Q);
  k_gemm_blas<<<dim3(16, 64), 256, 0, stream>>>(XD, M + 1 * (size_t)WSZ, K);
  k_gemm_blas<<<dim3(16, 64), 256, 0, stream>>>(XD, M + 2 * (size_t)WSZ, V);

  k_attn_np<<<dim3(128, 32), 256, 0, stream>>>(Q, K, V, ctx);

  k_ctxq_np<<<4096, 256, 0, stream>>>(ctx, cqm);

  k_gemm_blas<<<dim3(16, 64), 256, 0, stream>>>(cqm, M + 3 * (size_t)WSZ, out);
}